// Round 10
// baseline (1366.358 us; speedup 1.0000x reference)
//
#include <hip/hip_runtime.h>
#include <hip/hip_cooperative_groups.h>
#include <math.h>

namespace cg = cooperative_groups;
typedef float4 f4;
typedef float2 f2;

#define NT 512          // 8 waves/block; each wave owns 4 rows end-to-end
#define RB 32           // rows per block; GRID=256 (cooperative cap)

// ---------------- workspace float offsets ----------------
#define WS_WR    0          // WR[128][256]: [k][0:128]=W2T row k, [k][128:256]=R row k
#define WS_PART  32768      // [10][256] err partials
#define WS_TOTAL 35328

// ---------------- LDS float offsets (123.8 KB) ----------------------------
#define L_W1T   0           // [32][132+] W1T[j][h]=W1[h][j], k-quarter swizzled
#define L_C3T   4240        // [32 c][148] C3T[c][b], b-quarter swizzled
#define L_PT    8976        // [32 c][44]  PT[c][q], q-quarter swizzled
#define L_KZ    10384       // [7][32][36] k_z
#define L_KL    18448       // [7][32]
#define L_YZ    18672       // [32][36]
#define L_Y1Z   19824       // [32][36]
#define L_YL    20976       // [32]
#define L_Y1L   21008       // [32]
#define L_B1    21040
#define L_B2    21168
#define L_C0    21296
#define L_MISC  21328       // trP
#define L_RED8  21332       // [8] per-wave partials
#define L_WV    21340       // 8 waves x WVSZ private tiles (init alias region)
#define WVSZ    1200
#define WV_XW   0           // [~140] x transposed, swizzled
#define WV_HW   140         // [~528] h1, swizzled
#define WV_H2   668         // [~528] h2, swizzled
#define LDS_FLOATS 30940

// init aliases inside WV region (dead during init):
#define LI_GS    (L_WV + 0)      // [8][32]
#define LI_AAUG  (L_WV + 256)    // [8][16]
#define LI_AINVG (L_WV + 384)    // [8][32]
#define LI_P     (L_WV + 640)    // [32][32] P, then IP in place
#define LI_IPW3  (L_WV + 1664)   // [32][128]

__device__ const float ACO[5][5] = {
  { 0.2f, 0.f, 0.f, 0.f, 0.f },
  { (float)(3.0/40.0), (float)(9.0/40.0), 0.f, 0.f, 0.f },
  { (float)(44.0/45.0), (float)(-56.0/15.0), (float)(32.0/9.0), 0.f, 0.f },
  { (float)(19372.0/6561.0), (float)(-25360.0/2187.0), (float)(64448.0/6561.0), (float)(-212.0/729.0), 0.f },
  { (float)(9017.0/3168.0), (float)(-355.0/33.0), (float)(46732.0/5247.0), (float)(49.0/176.0), (float)(-5103.0/18656.0) }
};

#define B1C ((float)(35.0/384.0))
#define B3C ((float)(500.0/1113.0))
#define B4C ((float)(125.0/192.0))
#define B5C ((float)(-2187.0/6784.0))
#define B6C ((float)(11.0/84.0))

#define E1C ((float)(35.0/384.0 - 5179.0/57600.0))
#define E3C ((float)(500.0/1113.0 - 7571.0/16695.0))
#define E4C ((float)(125.0/192.0 - 393.0/640.0))
#define E5C ((float)(-2187.0/6784.0 + 92097.0/339200.0))
#define E6C ((float)(11.0/84.0 - 187.0/2100.0))
#define E7C ((float)(-1.0/40.0))

__device__ __forceinline__ f4 ld4(const float* p){ return *(const f4*)p; }
__device__ __forceinline__ void st4(float* p, f4 v){ *(f4*)p = v; }

// wave-private assemble: x = y + dtc*sum co[p]*k[p] for this wave's 4 rows
__device__ void assemble_wave(float* lds, int lane, int w, float dtc,
                              const float* co, int np)
{
  const int row = lane >> 4, c0 = 2 * (lane & 15);
  const int yo = (4 * w + row) * 36 + c0;
  f2 y = *(const f2*)&lds[L_YZ + yo];
  float sx = 0.f, sy = 0.f;
  for (int p = 0; p < np; p++){
    f2 kv = *(const f2*)&lds[L_KZ + p * 1152 + yo];
    sx += co[p] * kv.x; sy += co[p] * kv.y;
  }
  float* XW = &lds[L_WV + w * WVSZ + WV_XW];
  const int s0 = 4 * c0 + 4 * ((c0 >> 3) & 3);   // c0 even -> c0+1 same quarter
  XW[s0 + row]     = y.x + dtc * sx;
  XW[s0 + 4 + row] = y.y + dtc * sy;
  __threadfence_block();
}

// wave-private f-eval: XW -> L_KZ[kout] rows 4w..4w+3, L_KL[kout]
// lane = cg(16, 8 cols each) x kh(4, k-quarter)
__device__ void eval_wave(float* lds, const float* __restrict__ ws,
                          int lane, int w, float trP, int kout)
{
  const int cg = lane & 15, kh = lane >> 4;
  float* XW = &lds[L_WV + w * WVSZ + WV_XW];
  float* HW = &lds[L_WV + w * WVSZ + WV_HW];
  float* H2 = &lds[L_WV + w * WVSZ + WV_H2];

  // ---- phase 1: h1 = relu(x @ W1^T + b1), k-quarter split ----
  float a1[8][4];
#pragma unroll
  for (int i = 0; i < 8; i++)
#pragma unroll
    for (int j = 0; j < 4; j++) a1[i][j] = 0.f;
#pragma unroll
  for (int t = 0; t < 8; t++){
    const int k = kh * 8 + t;
    f4 av = ld4(&XW[4 * k + 4 * kh]);
    f4 b0 = ld4(&lds[L_W1T + k * 132 + 4 * kh + 8 * cg]);
    f4 b1v = ld4(&lds[L_W1T + k * 132 + 4 * kh + 8 * cg + 4]);
    const float* ap = (const float*)&av;
    const float* bp0 = (const float*)&b0;
    const float* bp1 = (const float*)&b1v;
#pragma unroll
    for (int i = 0; i < 4; i++)
#pragma unroll
      for (int j = 0; j < 4; j++){
        a1[i][j]     += bp0[i] * ap[j];
        a1[4 + i][j] += bp1[i] * ap[j];
      }
  }
#pragma unroll
  for (int i = 0; i < 8; i++)
#pragma unroll
    for (int j = 0; j < 4; j++){
      a1[i][j] += __shfl_xor(a1[i][j], 16);
      a1[i][j] += __shfl_xor(a1[i][j], 32);
    }
  if (kh == 0){
    f4 bb0 = ld4(&lds[L_B1 + 8 * cg]);
    f4 bb1 = ld4(&lds[L_B1 + 8 * cg + 4]);
    const float* bp0 = (const float*)&bb0;
    const float* bp1 = (const float*)&bb1;
    const int swz = 4 * ((cg >> 2) & 3);
#pragma unroll
    for (int i = 0; i < 8; i++){
      float bi = (i < 4) ? bp0[i] : bp1[i - 4];
      f4 hv; float* hp = (float*)&hv;
#pragma unroll
      for (int j = 0; j < 4; j++) hp[j] = fmaxf(a1[i][j] + bi, 0.f);
      st4(&HW[4 * (8 * cg + i) + swz], hv);
    }
  }
  __threadfence_block();

  // ---- phase 2: ah = h1@W2^T, at = m1^T R ; k-quarter split, WR stream ----
  float ah[8][4], at[8][4];
#pragma unroll
  for (int i = 0; i < 8; i++)
#pragma unroll
    for (int j = 0; j < 4; j++){ ah[i][j] = 0.f; at[i][j] = 0.f; }
  const f4* WR4 = (const f4*)&ws[WS_WR];   // row k = 64 f4: [0:32)=W2T, [32:64)=R
  const int kb = kh * 32;
  f4 buf[8];
#pragma unroll
  for (int e = 0; e < 2; e++){
    buf[4*e+0] = WR4[(kb + e) * 64 + 2 * cg];
    buf[4*e+1] = WR4[(kb + e) * 64 + 2 * cg + 1];
    buf[4*e+2] = WR4[(kb + e) * 64 + 32 + 2 * cg];
    buf[4*e+3] = WR4[(kb + e) * 64 + 32 + 2 * cg + 1];
  }
#pragma unroll 1
  for (int g = 0; g < 16; g++){
    f4 cur[8];
#pragma unroll
    for (int u = 0; u < 8; u++) cur[u] = buf[u];
    if (g < 15){
      const int kn = kb + 2 * (g + 1);
#pragma unroll
      for (int e = 0; e < 2; e++){
        buf[4*e+0] = WR4[(kn + e) * 64 + 2 * cg];
        buf[4*e+1] = WR4[(kn + e) * 64 + 2 * cg + 1];
        buf[4*e+2] = WR4[(kn + e) * 64 + 32 + 2 * cg];
        buf[4*e+3] = WR4[(kn + e) * 64 + 32 + 2 * cg + 1];
      }
    }
#pragma unroll
    for (int e = 0; e < 2; e++){
      const int k = kb + 2 * g + e;
      f4 av = ld4(&HW[4 * k + 4 * kh]);
      const float* ap = (const float*)&av;
      const float* wa = (const float*)&cur[4*e+0];
      const float* wb = (const float*)&cur[4*e+1];
      const float* ra = (const float*)&cur[4*e+2];
      const float* rb = (const float*)&cur[4*e+3];
      float m[4];
#pragma unroll
      for (int j = 0; j < 4; j++) m[j] = (ap[j] > 0.f) ? 1.f : 0.f;
#pragma unroll
      for (int i = 0; i < 4; i++)
#pragma unroll
        for (int j = 0; j < 4; j++){
          ah[i][j]     += wa[i] * ap[j];
          ah[4 + i][j] += wb[i] * ap[j];
          at[i][j]     += ra[i] * m[j];
          at[4 + i][j] += rb[i] * m[j];
        }
    }
  }
#pragma unroll
  for (int i = 0; i < 8; i++)
#pragma unroll
    for (int j = 0; j < 4; j++){
      ah[i][j] += __shfl_xor(ah[i][j], 16);
      ah[i][j] += __shfl_xor(ah[i][j], 32);
      at[i][j] += __shfl_xor(at[i][j], 16);
      at[i][j] += __shfl_xor(at[i][j], 32);
    }

  f4 b2a = ld4(&lds[L_B2 + 8 * cg]);
  f4 b2b = ld4(&lds[L_B2 + 8 * cg + 4]);
  const float* b2p0 = (const float*)&b2a;
  const float* b2p1 = (const float*)&b2b;
  float h2v[8][4]; float dl[4] = {0.f, 0.f, 0.f, 0.f};
#pragma unroll
  for (int i = 0; i < 8; i++){
    float bi = (i < 4) ? b2p0[i] : b2p1[i - 4];
#pragma unroll
    for (int j = 0; j < 4; j++){
      float pre = ah[i][j] + bi;
      h2v[i][j] = fmaxf(pre, 0.f);
      if (pre > 0.f) dl[j] += at[i][j];
    }
  }
#pragma unroll
  for (int mk = 1; mk < 16; mk <<= 1){
#pragma unroll
    for (int j = 0; j < 4; j++) dl[j] += __shfl_xor(dl[j], mk);
  }
  if (lane == 0){
#pragma unroll
    for (int j = 0; j < 4; j++)
      lds[L_KL + kout * 32 + 4 * w + j] = dl[j] + trP;
  }
  if (kh == 0){
    const int swz = 4 * ((cg >> 2) & 3);
#pragma unroll
    for (int i = 0; i < 8; i++){
      f4 hv; float* hp = (float*)&hv;
#pragma unroll
      for (int j = 0; j < 4; j++) hp[j] = h2v[i][j];
      st4(&H2[4 * (8 * cg + i) + swz], hv);
    }
  }
  __threadfence_block();

  // ---- phase 3: dz = -(h2 @ C3 + c0 + x @ P), b/q quarter split ----
  float a3[2][4] = {{0.f,0.f,0.f,0.f},{0.f,0.f,0.f,0.f}};
  const int cc0 = 2 * cg, cc1 = 2 * cg + 1;
  const int bb = kh * 32;
#pragma unroll 2
  for (int t = 0; t < 8; t++){
    const int b4 = bb + 4 * t;
    f4 cva = ld4(&lds[L_C3T + cc0 * 148 + b4 + 4 * kh]);
    f4 cvb = ld4(&lds[L_C3T + cc1 * 148 + b4 + 4 * kh]);
    const float* ca = (const float*)&cva;
    const float* cb = (const float*)&cvb;
#pragma unroll
    for (int u = 0; u < 4; u++){
      f4 av = ld4(&H2[4 * (b4 + u) + 4 * kh]);
      const float* ap = (const float*)&av;
#pragma unroll
      for (int j = 0; j < 4; j++){
        a3[0][j] += ap[j] * ca[u];
        a3[1][j] += ap[j] * cb[u];
      }
    }
  }
  const int qq = kh * 8;
#pragma unroll
  for (int t = 0; t < 2; t++){
    const int q4 = qq + 4 * t;
    f4 pva = ld4(&lds[L_PT + cc0 * 44 + q4 + 4 * kh]);
    f4 pvb = ld4(&lds[L_PT + cc1 * 44 + q4 + 4 * kh]);
    const float* pa = (const float*)&pva;
    const float* pb = (const float*)&pvb;
#pragma unroll
    for (int u = 0; u < 4; u++){
      f4 av = ld4(&XW[4 * (q4 + u) + 4 * kh]);
      const float* ap = (const float*)&av;
#pragma unroll
      for (int j = 0; j < 4; j++){
        a3[0][j] += ap[j] * pa[u];
        a3[1][j] += ap[j] * pb[u];
      }
    }
  }
#pragma unroll
  for (int j = 0; j < 4; j++){
    a3[0][j] += __shfl_xor(a3[0][j], 16);
    a3[0][j] += __shfl_xor(a3[0][j], 32);
    a3[1][j] += __shfl_xor(a3[1][j], 16);
    a3[1][j] += __shfl_xor(a3[1][j], 32);
  }
  if (kh == 0){
    float c0v = lds[L_C0 + cc0];
    float c1v = lds[L_C0 + cc1];
#pragma unroll
    for (int j = 0; j < 4; j++){
      f2 kv; kv.x = -(a3[0][j] + c0v); kv.y = -(a3[1][j] + c1v);
      *(f2*)&lds[L_KZ + kout * 1152 + (4 * w + j) * 36 + cc0] = kv;
    }
  }
  __threadfence_block();
}

__global__ void __launch_bounds__(NT, 2)
qpnf_kernel(const float* __restrict__ z, const float* __restrict__ Gw,
            const float* __restrict__ W1g, const float* __restrict__ b1g,
            const float* __restrict__ W2g, const float* __restrict__ b2g,
            const float* __restrict__ W3g, const float* __restrict__ b3g,
            const float* __restrict__ Tg, float* __restrict__ out,
            float* __restrict__ ws)
{
  __shared__ float lds[LDS_FLOATS];
  const int tid = threadIdx.x;
  const int bid = blockIdx.x;
  const int r0 = bid * RB;
  const int lane = tid & 63, w = tid >> 6;
  cg::grid_group grid = cg::this_grid();

  // ================= init =================
  if (tid < 128){ lds[L_B1 + tid] = b1g[tid]; lds[L_B2 + tid] = b2g[tid]; }
  if (tid < 256) lds[LI_GS + tid] = Gw[tid];
  __syncthreads();

  if (tid < 64){                              // A = G G^T (8x8), augmented
    int i = tid >> 3, j = tid & 7;
    float s = 0.f;
    for (int k = 0; k < 32; k++) s += lds[LI_GS + i * 32 + k] * lds[LI_GS + j * 32 + k];
    lds[LI_AAUG + i * 16 + j] = s;
    lds[LI_AAUG + i * 16 + 8 + j] = (i == j) ? 1.f : 0.f;
  }
  __syncthreads();
  if (tid == 0){                              // Gauss-Jordan, partial pivoting
    float* A = &lds[LI_AAUG];
    for (int c = 0; c < 8; c++){
      int p = c; float mx = fabsf(A[c * 16 + c]);
      for (int r = c + 1; r < 8; r++){
        float v = fabsf(A[r * 16 + c]);
        if (v > mx){ mx = v; p = r; }
      }
      if (p != c)
        for (int q = 0; q < 16; q++){ float t = A[c*16+q]; A[c*16+q] = A[p*16+q]; A[p*16+q] = t; }
      float pv = 1.0f / A[c * 16 + c];
      for (int q = 0; q < 16; q++) A[c * 16 + q] *= pv;
      for (int r = 0; r < 8; r++) if (r != c){
        float fct = A[r * 16 + c];
        for (int q = 0; q < 16; q++) A[r * 16 + q] -= fct * A[c * 16 + q];
      }
    }
  }
  __syncthreads();
  if (tid < 256){                              // AinvG[m][d]
    int m = tid >> 5, d = tid & 31;
    float s = 0.f;
    for (int q = 0; q < 8; q++) s += lds[LI_AAUG + m * 16 + 8 + q] * lds[LI_GS + q * 32 + d];
    lds[LI_AINVG + m * 32 + d] = s;
  }
  __syncthreads();
  for (int i2 = 0; i2 < 2; i2++){              // P[q][c] = (G^T AinvG)[q][c]
    int idx = tid + i2 * NT;
    int q = idx >> 5, c = idx & 31;
    float s = 0.f;
    for (int m = 0; m < 8; m++) s += lds[LI_GS + m * 32 + q] * lds[LI_AINVG + m * 32 + c];
    lds[LI_P + q * 32 + c] = s;
  }
  __syncthreads();
  for (int i2 = 0; i2 < 2; i2++){              // PT (transposed, q-swizzled)
    int idx = tid + i2 * NT;
    int c = idx >> 5, q = idx & 31;
    lds[L_PT + c * 44 + q + 4 * ((q >> 3) & 3)] = lds[LI_P + q * 32 + c];
  }
  if (tid == 0){
    float s = 0.f;
    for (int i = 0; i < 32; i++) s += lds[LI_P + i * 32 + i];
    lds[L_MISC] = s;                           // trP
  }
  __syncthreads();
  for (int i2 = 0; i2 < 2; i2++){              // IP = I - P in place
    int idx = tid + i2 * NT;
    int i = idx >> 5, j = idx & 31;
    lds[LI_P + i * 32 + j] = ((i == j) ? 1.f : 0.f) - lds[LI_P + i * 32 + j];
  }
  __syncthreads();
  for (int i8 = 0; i8 < 8; i8++){              // C3T[c][b] (b-swizzled)
    int idx = tid + i8 * NT;
    int c = idx >> 7, b = idx & 127;
    float s = 0.f;
    for (int i = 0; i < 32; i++) s += W3g[i * 128 + b] * lds[LI_P + i * 32 + c];
    lds[L_C3T + c * 148 + b + 4 * ((b >> 5) & 3)] = s;
  }
  if (tid < 32){                               // c0 = b3 @ IP
    float s = 0.f;
    for (int i = 0; i < 32; i++) s += b3g[i] * lds[LI_P + i * 32 + tid];
    lds[L_C0 + tid] = s;
  }
  for (int i8 = 0; i8 < 8; i8++){              // IPW3[j][b]
    int idx = tid + i8 * NT;
    int j = idx >> 7, b = idx & 127;
    float s = 0.f;
    for (int k = 0; k < 32; k++) s += lds[LI_P + j * 32 + k] * W3g[k * 128 + b];
    lds[LI_IPW3 + j * 128 + b] = s;
  }
  for (int i8 = 0; i8 < 8; i8++){              // W1T (k-quarter swizzled)
    int idx = tid + i8 * NT;
    int h = idx >> 5, j = idx & 31;
    lds[L_W1T + j * 132 + 4 * ((j >> 3) & 3) + h] = W1g[idx];
  }
  __syncthreads();
  if (bid < 128 && tid < 128){                 // R row a=bid -> WR[a][128+b]
    int a = bid;
    float s = 0.f;
    for (int j = 0; j < 32; j++) s += W1g[a * 32 + j] * lds[LI_IPW3 + j * 128 + tid];
    ws[WS_WR + a * 256 + 128 + tid] = s * W2g[tid * 128 + a];
  }
  if (bid >= 128 && tid < 128){                // W2T row a -> WR[a][b]
    int a = bid - 128;
    ws[WS_WR + a * 256 + tid] = W2g[tid * 128 + a];
  }
  if (tid < 256){                              // y0 -> LDS
    const int r = tid >> 3, jj = (tid & 7) * 4;
    st4(&lds[L_YZ + r * 36 + jj], ld4(&z[(r0 + r) * 32 + jj]));
  }
  if (tid < RB) lds[L_YL + tid] = 0.f;

  __syncthreads();
  const float trP = lds[L_MISC];
  const float t1 = 2.0f * Tg[0];

  grid.sync();

  // ================= main adaptive RK loop =================
  float t_cur = 0.f, dt_cur = 0.25f;
  bool prev_acc = false;

  for (int step = 0; step < 10; step++){
    if (t_cur >= t1 - 1e-9f) break;
    const float dtc = fminf(dt_cur, t1 - t_cur);

    // ---- stage 1 (wave-private) ----
    if (step == 0){
      assemble_wave(lds, lane, w, dtc, ACO[0], 0);
      eval_wave(lds, ws, lane, w, trP, 0);
    } else if (prev_acc){                      // FSAL: k1 = previous k7
      const int row = lane >> 4, c0 = 2 * (lane & 15);
      const int yo = (4 * w + row) * 36 + c0;
      *(f2*)&lds[L_KZ + yo] = *(const f2*)&lds[L_KZ + 6 * 1152 + yo];
      if (lane < 4) lds[L_KL + 4 * w + lane] = lds[L_KL + 6 * 32 + 4 * w + lane];
      __threadfence_block();
    }                                          // rejected: k1 unchanged

    // ---- stages 2..6 (wave-private, no block barriers) ----
    for (int s = 2; s <= 6; s++){
      assemble_wave(lds, lane, w, dtc, ACO[s - 2], s - 1);
      eval_wave(lds, ws, lane, w, trP, s - 1);
    }

    // ---- stage 7: y1 and k7 (wave-private) ----
    {
      const int row = lane >> 4, c0 = 2 * (lane & 15);
      const int yo = (4 * w + row) * 36 + c0;
      f2 y   = *(const f2*)&lds[L_YZ + yo];
      f2 k1v = *(const f2*)&lds[L_KZ + 0 * 1152 + yo];
      f2 k3v = *(const f2*)&lds[L_KZ + 2 * 1152 + yo];
      f2 k4v = *(const f2*)&lds[L_KZ + 3 * 1152 + yo];
      f2 k5v = *(const f2*)&lds[L_KZ + 4 * 1152 + yo];
      f2 k6v = *(const f2*)&lds[L_KZ + 5 * 1152 + yo];
      f2 x;
      x.x = y.x + dtc * (B1C*k1v.x + B3C*k3v.x + B4C*k4v.x + B5C*k5v.x + B6C*k6v.x);
      x.y = y.y + dtc * (B1C*k1v.y + B3C*k3v.y + B4C*k4v.y + B5C*k5v.y + B6C*k6v.y);
      *(f2*)&lds[L_Y1Z + yo] = x;
      float* XW = &lds[L_WV + w * WVSZ + WV_XW];
      const int s0 = 4 * c0 + 4 * ((c0 >> 3) & 3);
      XW[s0 + row]     = x.x;
      XW[s0 + 4 + row] = x.y;
      if (lane < 4){
        int n = 4 * w + lane;
        float s = B1C * lds[L_KL + 0*32 + n] + B3C * lds[L_KL + 2*32 + n]
                + B4C * lds[L_KL + 3*32 + n] + B5C * lds[L_KL + 4*32 + n]
                + B6C * lds[L_KL + 5*32 + n];
        lds[L_Y1L + n] = lds[L_YL + n] + dtc * s;
      }
      __threadfence_block();
    }
    eval_wave(lds, ws, lane, w, trP, 6);

    // ---- error partial (wave-private then block/grid reduce) ----
    float sacc = 0.f;
    {
      const int row = lane >> 4, c0 = 2 * (lane & 15);
      const int yo = (4 * w + row) * 36 + c0;
      f2 k1v = *(const f2*)&lds[L_KZ + 0 * 1152 + yo];
      f2 k3v = *(const f2*)&lds[L_KZ + 2 * 1152 + yo];
      f2 k4v = *(const f2*)&lds[L_KZ + 3 * 1152 + yo];
      f2 k5v = *(const f2*)&lds[L_KZ + 4 * 1152 + yo];
      f2 k6v = *(const f2*)&lds[L_KZ + 5 * 1152 + yo];
      f2 k7v = *(const f2*)&lds[L_KZ + 6 * 1152 + yo];
      f2 yv  = *(const f2*)&lds[L_YZ + yo];
      f2 y1v = *(const f2*)&lds[L_Y1Z + yo];
      float ev, tol, q;
      ev = dtc * (E1C*k1v.x + E3C*k3v.x + E4C*k4v.x + E5C*k5v.x + E6C*k6v.x + E7C*k7v.x);
      tol = 1e-5f + 1e-5f * fmaxf(fabsf(yv.x), fabsf(y1v.x)); q = ev / tol; sacc += q * q;
      ev = dtc * (E1C*k1v.y + E3C*k3v.y + E4C*k4v.y + E5C*k5v.y + E6C*k6v.y + E7C*k7v.y);
      tol = 1e-5f + 1e-5f * fmaxf(fabsf(yv.y), fabsf(y1v.y)); q = ev / tol; sacc += q * q;
      if (lane < 4){
        int n = 4 * w + lane;
        float evl = dtc * (E1C * lds[L_KL + 0*32 + n] + E3C * lds[L_KL + 2*32 + n]
                  + E4C * lds[L_KL + 3*32 + n] + E5C * lds[L_KL + 4*32 + n]
                  + E6C * lds[L_KL + 5*32 + n] + E7C * lds[L_KL + 6*32 + n]);
        float toll = 1e-5f + 1e-5f * fmaxf(fabsf(lds[L_YL + n]), fabsf(lds[L_Y1L + n]));
        float ql = evl / toll; sacc += ql * ql;
      }
    }
#pragma unroll
    for (int mk = 1; mk < 64; mk <<= 1) sacc += __shfl_xor(sacc, mk);
    if (lane == 0) lds[L_RED8 + w] = sacc;
    __syncthreads();
    if (tid == 0){
      float s = 0.f;
      for (int i = 0; i < 8; i++) s += lds[L_RED8 + i];
      ws[WS_PART + step * 256 + bid] = s;
    }
    grid.sync();

    // deterministic global reduction (RED256 aliases WV — dead between steps)
    float* red = &lds[L_WV];
    if (tid < 256) red[tid] = ws[WS_PART + step * 256 + tid];
    __syncthreads();
    for (int o = 128; o > 0; o >>= 1){
      if (tid < o) red[tid] += red[tid + o];
      __syncthreads();
    }
    const float errn = sqrtf(red[0] / 270336.0f);
    __syncthreads();

    const bool accept = (errn <= 1.0f);
    if (accept){
      if (tid < 256){
        const int r = tid >> 3, jj = (tid & 7) * 4;
        st4(&lds[L_YZ + r * 36 + jj], ld4(&lds[L_Y1Z + r * 36 + jj]));
      }
      if (tid < RB) lds[L_YL + tid] = lds[L_Y1L + tid];
      t_cur += dtc;
    }
    float fac = 0.9f * powf(errn, -0.2f);
    fac = fminf(fmaxf(fac, 0.2f), 10.0f);
    dt_cur = fminf(fmaxf(dtc * fac, 1e-6f), t1);
    prev_acc = accept;
    __syncthreads();
  }

  // ---- output: yT[:, :d] ----
  __syncthreads();
  if (tid < 256){
    const int r = tid >> 3, jj = (tid & 7) * 4;
    st4(&out[(r0 + r) * 32 + jj], ld4(&lds[L_YZ + r * 36 + jj]));
  }
}

extern "C" void kernel_launch(void* const* d_in, const int* in_sizes, int n_in,
                              void* d_out, int out_size, void* d_ws, size_t ws_size,
                              hipStream_t stream)
{
  (void)in_sizes; (void)n_in; (void)out_size;
  const float* z  = (const float*)d_in[0];
  const float* Gw = (const float*)d_in[1];
  const float* W1 = (const float*)d_in[2];
  const float* b1 = (const float*)d_in[3];
  const float* W2 = (const float*)d_in[4];
  const float* b2 = (const float*)d_in[5];
  const float* W3 = (const float*)d_in[6];
  const float* b3 = (const float*)d_in[7];
  const float* T  = (const float*)d_in[8];
  float* out = (float*)d_out;
  float* ws  = (float*)d_ws;
  if (ws_size < (size_t)WS_TOTAL * sizeof(float)) return;

  void* args[] = { (void*)&z, (void*)&Gw, (void*)&W1, (void*)&b1, (void*)&W2,
                   (void*)&b2, (void*)&W3, (void*)&b3, (void*)&T, (void*)&out,
                   (void*)&ws };
  hipLaunchCooperativeKernel((const void*)qpnf_kernel, dim3(256), dim3(NT),
                             args, 0, stream);
}